// Round 17
// baseline (128.635 us; speedup 1.0000x reference)
//
#include <hip/hip_runtime.h>
#include <hip/hip_bf16.h>

// ---------- types ----------
typedef __attribute__((ext_vector_type(8))) short s16x8;
typedef __attribute__((ext_vector_type(4))) short s16x4;
typedef __attribute__((ext_vector_type(4))) float f32x4;

__device__ __forceinline__ float b2f(short s) {
  return __uint_as_float(((unsigned)(unsigned short)s) << 16);
}
__device__ __forceinline__ short f2b(float f) {
  unsigned u = __float_as_uint(f);
  unsigned r = u + 0x7fffu + ((u >> 16) & 1u);   // round-to-nearest-even
  return (short)(r >> 16);
}

// async global->LDS, 16B per lane; LDS dest = wave-uniform base + lane*16
__device__ __forceinline__ void gload16(const short* g, short* l) {
  __builtin_amdgcn_global_load_lds((const __attribute__((address_space(1))) void*)g,
                                   (__attribute__((address_space(3))) void*)l, 16, 0, 0);
}

// ---------- problem constants ----------
#define BATCH 64
#define NP    196
#define TL    77
#define DM    512
#define CIMG  1024

// unified GEMM LDS carve (50176 B total -> 3 blocks/CU)
#define SM_AS   0          // short As[2][64*64]   = 16384 B
#define SM_BS   16384      // short Bs[2][128*64]  = 32768 B
#define SM_PC   49152      // float pc[2][128]     = 1024 B
#define SM_SIZE 50176

// stream-transpose of one (b, c-stripe-of-64): the source region
// img[b][c0..c0+64)[*] is ONE CONTIGUOUS 50KB block -> flat float4 streaming
// load (fully coalesced, sequential), f2b into a 64x202 bf16 LDS tile
// (stride 202 -> ~4-way max bank aliasing on the transposed read), then
// s16x8 stores. Needs 25856 B of LDS.
__device__ __forceinline__ void img_transpose_stripe(
    short* lds, const float* __restrict__ img, short* __restrict__ aimg, int bb) {
  int tid = threadIdx.x;
  int b = bb >> 4, c0 = (bb & 15) * 64;
  const float4* src = (const float4*)(img + (size_t)b * CIMG * NP + (size_t)c0 * NP);
  // load: 3136 float4s flat; f = cl*49 + c4  (row cl = c-local, 49 f4/row)
  #pragma unroll
  for (int it = 0; it < 13; it++) {
    int f = it * 256 + tid;
    if (f < 3136) {
      float4 v = src[f];
      int cl = f / 49, c4 = f - cl * 49;
      s16x4 o;
      o[0] = f2b(v.x); o[1] = f2b(v.y); o[2] = f2b(v.z); o[3] = f2b(v.w);
      *(s16x4*)&lds[cl * 202 + c4 * 4] = o;
    }
  }
  __syncthreads();
  // store: 196 n-rows x 8 c-chunks of 8 shorts
  short* ob = aimg + (size_t)b * NP * CIMG;
  #pragma unroll
  for (int it = 0; it < 7; it++) {
    int task = it * 256 + tid;
    if (task < 1568) {
      int n = task >> 3, cc = task & 7;
      s16x8 o;
      #pragma unroll
      for (int q = 0; q < 8; q++) o[q] = lds[(cc * 8 + q) * 202 + n];
      *(s16x8*)&ob[(size_t)n * CIMG + c0 + cc * 8] = o;
    }
  }
}

// ---------- prep (1-D grid, 4176 blocks; transpose FIRST = long poles) ----------
// [0,1024):     img stream-transpose (b,c-stripe), 6 blocks/CU (25.9KB LDS)
// [1024,1536):  Wi f32 -> wiB bf16 straight cast
// [1536,2048):  Wt transpose
// [2048,3072):  Wq,Wk,Wv,Wo transposes
// [3072,4096):  txt cast
// [4096,4160):  zero partA||partC
// [4160,4176):  biasQ e-slice partials
__global__ __launch_bounds__(256)
void prep_kernel(const float* __restrict__ Wi, const float* __restrict__ Wt,
                 const float* __restrict__ Wq, const float* __restrict__ Wk,
                 const float* __restrict__ Wv, const float* __restrict__ Wo,
                 short* __restrict__ wiB, short* __restrict__ WtT,
                 short* __restrict__ WqT, short* __restrict__ WkT,
                 short* __restrict__ WvT, short* __restrict__ WoT,
                 const float* __restrict__ txt, short* __restrict__ textB,
                 float* __restrict__ partZero,
                 const float* __restrict__ bi, float* __restrict__ bqPart,
                 const float* __restrict__ img, short* __restrict__ aimg) {
  int blk = blockIdx.x;
  __shared__ __align__(16) short sprep[64 * 202];   // 25856 B; overlaid below
  int tid = threadIdx.x;
  if (blk < 1024) {
    img_transpose_stripe(sprep, img, aimg, blk);
    return;
  }
  if (blk < 1536) {
    int gid = (blk - 1024) * 256 + tid;
    float4 v = ((const float4*)Wi)[gid];
    s16x4 o;
    o[0] = f2b(v.x); o[1] = f2b(v.y); o[2] = f2b(v.z); o[3] = f2b(v.w);
    ((s16x4*)wiB)[gid] = o;
    return;
  }
  if (blk < 3072) {
    float* raw = (float*)sprep;          // 32x33 f32 = 4224 B < 25856 B
    const float* W; short* WT; int K, k0, n0;
    if (blk < 2048) {
      int bb = blk - 1536;
      W = Wt; WT = WtT; K = 1024;
      k0 = (bb & 31) * 32; n0 = (bb >> 5) * 32;
    } else {
      int bb = blk - 2048;
      int w = bb >> 8;
      switch (w) {
        case 0: W = Wq; WT = WqT; break;
        case 1: W = Wk; WT = WkT; break;
        case 2: W = Wv; WT = WvT; break;
        default: W = Wo; WT = WoT; break;
      }
      K = 512;
      k0 = (bb & 15) * 32; n0 = ((bb >> 4) & 15) * 32;
    }
    int tx = tid & 31, ty = tid >> 5;   // ty 0..7
    #pragma unroll
    for (int i = 0; i < 4; i++)
      raw[(ty + i * 8) * 33 + tx] = W[(size_t)(k0 + ty + i * 8) * 512 + n0 + tx];
    __syncthreads();
    #pragma unroll
    for (int i = 0; i < 4; i++)
      WT[(size_t)(n0 + ty + i * 8) * K + k0 + tx] = f2b(raw[tx * 33 + ty + i * 8]);
    return;
  }
  if (blk < 4096) {
    int fb = blk - 3072;
    int n4 = (int)((size_t)BATCH * TL * 1024 / 4);
    for (int i = fb * 256 + tid; i < n4; i += 1024 * 256) {
      float4 v = ((const float4*)txt)[i];
      s16x4 o;
      o[0] = f2b(v.x); o[1] = f2b(v.y); o[2] = f2b(v.z); o[3] = f2b(v.w);
      ((s16x4*)textB)[i] = o;
    }
    return;
  }
  if (blk < 4160) {
    int id = (blk - 4096) * 256 + tid;   // exactly [0,16384)
    ((float4*)partZero)[id] = make_float4(0.f, 0.f, 0.f, 0.f);
    return;
  }
  // biasQ partial: slice s covers e in [s*32, s*32+32)
  int s = blk - 4160, d0 = tid * 2;
  float a0 = 0.f, a1 = 0.f;
  #pragma unroll
  for (int i = 0; i < 32; i++) {
    int e = s * 32 + i;
    float bie = bi[e];
    a0 += bie * Wq[(size_t)e * 512 + d0];
    a1 += bie * Wq[(size_t)e * 512 + d0 + 1];
  }
  bqPart[s * 512 + d0] = a0;
  bqPart[s * 512 + d0 + 1] = a1;
}

// ---------- MFMA GEMM core (round-11 proven): BM=64, BN=128, BK=64 ----------
// Depth-2 counted-vmcnt pipeline (vmcnt never 0 mid-loop) + issue-early
// staging: vmcnt(6) -> barrier -> ds_read frags -> lgkmcnt(0) -> barrier ->
// stage(t+2) -> MFMAx16. XOR-swizzled LDS. 50KB LDS -> 3 blocks/CU.
__device__ __forceinline__ void gemm_core(
    short (*As)[64 * 64], short (*Bs)[128 * 64], float (*pc)[128],
    const short* __restrict__ A, const short* __restrict__ BT,
    const float* __restrict__ bias, const float* __restrict__ bias2,
    float* __restrict__ outF, short* __restrict__ outB,
    float* __restrict__ part, int rowsPerB,
    int bm, int bn, int M, int K, int N) {
  int tid = threadIdx.x, wave = tid >> 6, lane = tid & 63;
  int r = lane & 15, kg = lane >> 4, rr7 = r & 7;
  int wr = (wave >> 1) * 32, wc = (wave & 1) * 64;
  int l8 = lane >> 3, g8 = lane & 7;
  int scol = ((g8 ^ l8) << 3);          // swizzled source k-offset (elems)
  const short* gA = A + (size_t)(bm + wave * 16 + l8) * K + scol;
  const short* gB = BT + (size_t)(bn + wave * 32 + l8) * K + scol;

  f32x4 acc[2][4];
  #pragma unroll
  for (int i = 0; i < 2; i++)
    #pragma unroll
    for (int j = 0; j < 4; j++) acc[i][j] = (f32x4){0.f, 0.f, 0.f, 0.f};

  auto stage = [&](int buf, int k0) {   // 6 global_load_lds per wave
    #pragma unroll
    for (int j = 0; j < 2; j++)
      gload16(gA + (size_t)(j * 8) * K + k0, &As[buf][(wave * 16 + j * 8) * 64]);
    #pragma unroll
    for (int j = 0; j < 4; j++)
      gload16(gB + (size_t)(j * 8) * K + k0, &Bs[buf][(wave * 32 + j * 8) * 64]);
  };

  if (part) pc[tid >> 7][tid & 127] = 0.f;
  stage(0, 0);
  stage(1, 64);
  int nt = K >> 6;
  for (int t = 0; t < nt; t++) {
    if (t + 1 < nt) asm volatile("s_waitcnt vmcnt(6)" ::: "memory");
    else            asm volatile("s_waitcnt vmcnt(0)" ::: "memory");
    __builtin_amdgcn_s_barrier();
    asm volatile("" ::: "memory");
    int buf = t & 1;
    s16x8 af[2][2], bf[4][2];
    #pragma unroll
    for (int ks = 0; ks < 2; ks++) {
      int gsw = (((ks << 2) + kg) ^ rr7) << 3;   // swizzled granule (elems)
      #pragma unroll
      for (int i = 0; i < 2; i++)
        af[i][ks] = *(const s16x8*)&As[buf][(wr + i * 16 + r) * 64 + gsw];
      #pragma unroll
      for (int j = 0; j < 4; j++)
        bf[j][ks] = *(const s16x8*)&Bs[buf][(wc + j * 16 + r) * 64 + gsw];
    }
    asm volatile("s_waitcnt lgkmcnt(0)" ::: "memory");   // reads COMPLETE
    __builtin_amdgcn_sched_barrier(0);
    if (t + 2 < nt) {
      __builtin_amdgcn_s_barrier();      // all waves done sampling buf
      asm volatile("" ::: "memory");
      stage(buf, (t + 2) << 6);          // prefetch flies under the MFMAs
      __builtin_amdgcn_sched_barrier(0);
    }
    #pragma unroll
    for (int ks = 0; ks < 2; ks++)
      #pragma unroll
      for (int i = 0; i < 2; i++)
        #pragma unroll
        for (int j = 0; j < 4; j++)
          acc[i][j] = __builtin_amdgcn_mfma_f32_16x16x32_bf16(af[i][ks], bf[j][ks], acc[i][j], 0, 0, 0);
  }

  // epilogue: C/D layout col=lane&15, row=(lane>>4)*4+reg
  int bnd = part ? (bm / rowsPerB + 1) * rowsPerB : 0x7fffffff;
  #pragma unroll
  for (int i = 0; i < 2; i++) {
    float ps[4][2] = {{0.f, 0.f}, {0.f, 0.f}, {0.f, 0.f}, {0.f, 0.f}};
    #pragma unroll
    for (int rr = 0; rr < 4; rr++) {
      int row = bm + wr + i * 16 + kg * 4 + rr;
      int slot = (row >= bnd) ? 1 : 0;
      #pragma unroll
      for (int j = 0; j < 4; j++) {
        int col = bn + wc + j * 16 + r;
        float bval = (col < 512) ? bias[col] : bias2[col - 512];
        float v = acc[i][j][rr] + bval;
        if (outF) outF[(size_t)row * N + col] = v;
        if (outB) outB[(size_t)row * N + col] = f2b(v);
        ps[j][slot] += v;
      }
    }
    if (part) {
      #pragma unroll
      for (int j = 0; j < 4; j++) {
        atomicAdd(&pc[0][wc + j * 16 + r], ps[j][0]);
        if (ps[j][1] != 0.f) atomicAdd(&pc[1][wc + j * 16 + r], ps[j][1]);
      }
    }
  }
  if (part) {
    __syncthreads();
    int slot = tid >> 7, c = tid & 127;
    int b = bm / rowsPerB + slot;
    bool valid = (slot == 0) || (bnd <= bm + 63);
    if (valid && b < M / rowsPerB)
      atomicAdd(&part[(size_t)b * 512 + bn + c], pc[slot][c]);
  }
}

// two independent GEMMs in one launch, block-range dispatched.
// GEMM set 0: [0,g0); GEMM set 1: [g0,gridDim). g0 multiple of 8.
// Set 0 optionally finalizes biasQ = bqVec + sum_s bqPart[s][:].
__global__ __launch_bounds__(256)
void gemm_two(int g0,
    const short* A0, const short* BT0, const float* b0a, const float* b0b,
    float* oF0, short* oB0, float* p0, int rpb0, int M0, int K0, int N0, int lny0,
    const float* bqPart, const float* bqVec, float* bqOut,
    const short* A1, const short* BT1, const float* b1a, const float* b1b,
    float* oF1, short* oB1, float* p1, int rpb1, int M1, int K1, int N1, int lny1) {
  __shared__ __align__(16) char smem[SM_SIZE];
  short (*As)[64 * 64] = (short (*)[64 * 64])(smem + SM_AS);
  short (*Bs)[128 * 64] = (short (*)[128 * 64])(smem + SM_BS);
  float (*pc)[128] = (float (*)[128])(smem + SM_PC);
  int bid = blockIdx.x;
  if (bid < g0) {
    int nwg = g0, orig = bid;
    int q8 = nwg >> 3, rm = nwg & 7;
    int xcd = orig & 7, idx = orig >> 3;
    int lin = (xcd < rm ? xcd * (q8 + 1) : rm * (q8 + 1) + (xcd - rm) * q8) + idx;
    if (bqOut && threadIdx.x < 16 && lin * 16 + 15 < 512) {
      int d = lin * 16 + threadIdx.x;
      float a = bqVec[d];
      #pragma unroll
      for (int s = 0; s < 16; s++) a += bqPart[s * 512 + d];
      bqOut[d] = a;
    }
    int bx = lin >> lny0, by = lin & ((1 << lny0) - 1);
    gemm_core(As, Bs, pc, A0, BT0, b0a, b0b, oF0, oB0, p0, rpb0,
              bx * 64, by * 128, M0, K0, N0);
  } else {
    int nwg = gridDim.x - g0, orig = bid - g0;
    int q8 = nwg >> 3, rm = nwg & 7;
    int xcd = orig & 7, idx = orig >> 3;
    int lin = (xcd < rm ? xcd * (q8 + 1) : rm * (q8 + 1) + (xcd - rm) * q8) + idx;
    int bx = lin >> lny1, by = lin & ((1 << lny1) - 1);
    gemm_core(As, Bs, pc, A1, BT1, b1a, b1b, oF1, oB1, p1, rpb1,
              bx * 64, by * 128, M1, K1, N1);
  }
}

// attn-out GEMM [0,g1) + meanw range [g1,..): 2 (b,n) rows per 256-thr block.
__global__ __launch_bounds__(256)
void gemm_meanw(int g1,
    const short* __restrict__ A, const short* __restrict__ BT,
    const float* __restrict__ bias, const float* __restrict__ bias2,
    float* __restrict__ outF, short* __restrict__ outB,
    float* __restrict__ part, int rowsPerB, int M, int K, int N, int lny,
    const short* __restrict__ wAll, float* __restrict__ outW) {
  __shared__ __align__(16) char smem[SM_SIZE];
  short (*As)[64 * 64] = (short (*)[64 * 64])(smem + SM_AS);
  short (*Bs)[128 * 64] = (short (*)[128 * 64])(smem + SM_BS);
  float (*pc)[128] = (float (*)[128])(smem + SM_PC);
  int bid = blockIdx.x, tid = threadIdx.x;
  if (bid >= g1) {
    float* ws = (float*)smem;             // [2][8][80] overlay, 5.1KB
    int half = tid >> 7, t = tid & 127;
    int bn = (bid - g1) * 2 + half;       // < 12544
    int b = bn / 196, n = bn - b * 196;
    if (t < 80) {
      int h = t / 10, cc = t - h * 10;
      s16x8 v = *(const s16x8*)&wAll[(((size_t)(b * 8 + h)) * 196 + n) * 80 + cc * 8];
      #pragma unroll
      for (int j = 0; j < 8; j++) ws[half * 640 + h * 80 + cc * 8 + j] = b2f(v[j]);
    }
    __syncthreads();
    if (t < 77) {
      float s = 0.f;
      #pragma unroll
      for (int h = 0; h < 8; h++) s += ws[half * 640 + h * 80 + t];
      outW[(size_t)bn * 77 + t] = s * 0.125f;
    }
    return;
  }
  int nwg = g1, orig = bid;
  int q8 = nwg >> 3, rm = nwg & 7;
  int xcd = orig & 7, idx = orig >> 3;
  int lin = (xcd < rm ? xcd * (q8 + 1) : rm * (q8 + 1) + (xcd - rm) * q8) + idx;
  int bx = lin >> lny, by = lin & ((1 << lny) - 1);
  gemm_core(As, Bs, pc, A, BT, bias, bias2, outF, outB, part, rowsPerB,
            bx * 64, by * 128, M, K, N);
}

// ---------- MFMA attention: one block per (b,h), 4 waves ----------
// kvB layout: [B*TL][1024] bf16, cols 0..511 = k, 512..1023 = v
// wAll layout: [bh][196][80] bf16 (cols 77..79 junk-zero)
__global__ __launch_bounds__(256)
void attn_kernel(const short* __restrict__ qB, const short* __restrict__ kvB,
                 short* __restrict__ attnB, short* __restrict__ wAll) {
  __shared__ short kls[80 * 72];
  __shared__ short vtls[64 * 104];
  __shared__ short pls[4][16 * 104];
  int bh = blockIdx.x, b = bh >> 3, h = bh & 7;
  int tid = threadIdx.x, wave = tid >> 6, lane = tid & 63;
  int r = lane & 15, kg = lane >> 4;

  for (int i = lane; i < 208; i += 64)
    *(s16x8*)&pls[wave][i * 8] = (s16x8){0, 0, 0, 0, 0, 0, 0, 0};

  for (int idx = tid; idx < 80 * 8; idx += 256) {
    int t = idx >> 3, c8 = (idx & 7) << 3;
    s16x8 v = (s16x8){0, 0, 0, 0, 0, 0, 0, 0};
    if (t < 77) v = *(const s16x8*)&kvB[((size_t)(b * TL + t)) * 1024 + h * 64 + c8];
    *(s16x8*)&kls[t * 72 + c8] = v;
  }
  for (int idx = tid; idx < 64 * 12; idx += 256) {
    int d = idx & 63, t8 = idx >> 6;
    s16x8 v;
    #pragma unroll
    for (int j = 0; j < 8; j++) {
      int t = t8 * 8 + j;
      v[j] = (t < 77) ? kvB[((size_t)(b * TL + t)) * 1024 + 512 + h * 64 + d] : (short)0;
    }
    *(s16x8*)&vtls[d * 104 + t8 * 8] = v;
  }
  __syncthreads();

  s16x8 vf[4][3];
  #pragma unroll
  for (int jd = 0; jd < 4; jd++)
    #pragma unroll
    for (int kk = 0; kk < 3; kk++)
      vf[jd][kk] = *(const s16x8*)&vtls[(jd * 16 + r) * 104 + kg * 8 + kk * 32];

  for (int mf = wave; mf < 13; mf += 4) {
    int m0 = mf * 16;
    int qrow = m0 + r; if (qrow > 195) qrow = 195;
    const short* qp = qB + ((size_t)(b * NP + qrow)) * 512 + h * 64 + kg * 8;
    s16x8 qf0 = *(const s16x8*)qp;
    s16x8 qf1 = *(const s16x8*)(qp + 32);

    f32x4 s[5];
    #pragma unroll
    for (int j = 0; j < 5; j++) s[j] = (f32x4){0.f, 0.f, 0.f, 0.f};
    __builtin_amdgcn_s_setprio(1);
    #pragma unroll
    for (int j = 0; j < 5; j++) {
      s16x8 kf0 = *(const s16x8*)&kls[(j * 16 + r) * 72 + kg * 8];
      s16x8 kf1 = *(const s16x8*)&kls[(j * 16 + r) * 72 + kg * 8 + 32];
      s[j] = __builtin_amdgcn_mfma_f32_16x16x32_bf16(qf0, kf0, s[j], 0, 0, 0);
      s[j] = __builtin_amdgcn_mfma_f32_16x16x32_bf16(qf1, kf1, s[j], 0, 0, 0);
    }
    __builtin_amdgcn_s_setprio(0);
    float st[5][4];
    float mx[4] = {-3e38f, -3e38f, -3e38f, -3e38f};
    #pragma unroll
    for (int j = 0; j < 5; j++) {
      bool valid = (j * 16 + r) < 77;
      #pragma unroll
      for (int rr = 0; rr < 4; rr++) {
        float v = valid ? s[j][rr] * 0.125f : -3e38f;
        st[j][rr] = v;
        mx[rr] = fmaxf(mx[rr], v);
      }
    }
    #pragma unroll
    for (int m = 1; m < 16; m <<= 1)
      #pragma unroll
      for (int rr = 0; rr < 4; rr++)
        mx[rr] = fmaxf(mx[rr], __shfl_xor(mx[rr], m, 64));
    float sm[4] = {0.f, 0.f, 0.f, 0.f};
    #pragma unroll
    for (int j = 0; j < 5; j++)
      #pragma unroll
      for (int rr = 0; rr < 4; rr++) {
        float e = __expf(st[j][rr] - mx[rr]);
        st[j][rr] = e;
        sm[rr] += e;
      }
    #pragma unroll
    for (int m = 1; m < 16; m <<= 1)
      #pragma unroll
      for (int rr = 0; rr < 4; rr++)
        sm[rr] += __shfl_xor(sm[rr], m, 64);
    float rinv[4];
    #pragma unroll
    for (int rr = 0; rr < 4; rr++) rinv[rr] = 1.f / sm[rr];

    #pragma unroll
    for (int j = 0; j < 5; j++) {
      int t = j * 16 + r;
      #pragma unroll
      for (int rr = 0; rr < 4; rr++)
        pls[wave][(kg * 4 + rr) * 104 + t] = f2b(st[j][rr] * rinv[rr]);
    }
    asm volatile("s_waitcnt lgkmcnt(0)" ::: "memory");
    __builtin_amdgcn_sched_barrier(0);

    // vectorized wAll store: 16 rows x 10 chunks of 8 shorts (stride 80)
    #pragma unroll
    for (int i2 = 0; i2 < 3; i2++) {
      int cid = lane + i2 * 64;
      if (cid < 160) {
        int row = cid / 10, cc = cid - row * 10;
        int grow = m0 + row;
        if (grow < 196)
          *(s16x8*)&wAll[((size_t)bh * 196 + grow) * 80 + cc * 8] =
              *(const s16x8*)&pls[wave][row * 104 + cc * 8];
      }
    }

    s16x8 pf[3];
    #pragma unroll
    for (int kk = 0; kk < 3; kk++)
      pf[kk] = *(const s16x8*)&pls[wave][r * 104 + kg * 8 + kk * 32];
    f32x4 o[4];
    #pragma unroll
    for (int jd = 0; jd < 4; jd++) o[jd] = (f32x4){0.f, 0.f, 0.f, 0.f};
    __builtin_amdgcn_s_setprio(1);
    #pragma unroll
    for (int kk = 0; kk < 3; kk++)
      #pragma unroll
      for (int jd = 0; jd < 4; jd++)
        o[jd] = __builtin_amdgcn_mfma_f32_16x16x32_bf16(pf[kk], vf[jd][kk], o[jd], 0, 0, 0);
    __builtin_amdgcn_s_setprio(0);
    #pragma unroll
    for (int jd = 0; jd < 4; jd++)
      #pragma unroll
      for (int rr = 0; rr < 4; rr++) {
        int row = m0 + kg * 4 + rr;
        if (row < 196)
          attnB[((size_t)(b * NP + row)) * 512 + h * 64 + jd * 16 + r] = f2b(o[jd][rr]);
      }
  }
}

// ---------- fused finalize: means + l2-normalize + 64x64 cosine scores ----------
__global__ __launch_bounds__(256)
void final_kernel(const float* __restrict__ partA, const float* __restrict__ partC,
                  float* __restrict__ oAvg, float* __restrict__ oCls,
                  float* __restrict__ outScore) {
  __shared__ float alsA[512];
  __shared__ float red[4];
  __shared__ float rnAs;
  int b = blockIdx.x, tid = threadIdx.x;
  int wave = tid >> 6, lane = tid & 63;
  int c0 = tid * 2;
  float a0 = partA[(size_t)b * 512 + c0] * (1.f / 196.f);
  float a1 = partA[(size_t)b * 512 + c0 + 1] * (1.f / 196.f);
  float t0 = partC[(size_t)b * 512 + c0] * (1.f / 77.f);
  float t1 = partC[(size_t)b * 512 + c0 + 1] * (1.f / 77.f);
  oAvg[(size_t)b * 512 + c0] = a0; oAvg[(size_t)b * 512 + c0 + 1] = a1;
  oCls[(size_t)b * 512 + c0] = t0; oCls[(size_t)b * 512 + c0 + 1] = t1;
  alsA[c0] = a0; alsA[c0 + 1] = a1;
  float sq = a0 * a0 + a1 * a1;
  #pragma unroll
  for (int off = 32; off > 0; off >>= 1) sq += __shfl_down(sq, off, 64);
  if (lane == 0) red[wave] = sq;
  __syncthreads();
  if (tid == 0) rnAs = 1.f / fmaxf(sqrtf(red[0] + red[1] + red[2] + red[3]), 1e-8f);
  __syncthreads();
  float rnA = rnAs;
  float aReg[8];
  #pragma unroll
  for (int k = 0; k < 8; k++) aReg[k] = alsA[lane + k * 64];
  for (int j = wave * 16; j < wave * 16 + 16; j++) {
    float dot = 0.f, nrm = 0.f;
    #pragma unroll
    for (int k = 0; k < 8; k++) {
      float cv = partC[(size_t)j * 512 + lane + k * 64];
      dot += aReg[k] * cv;
      nrm += cv * cv;
    }
    #pragma unroll
    for (int off = 32; off > 0; off >>= 1) {
      dot += __shfl_down(dot, off, 64);
      nrm += __shfl_down(nrm, off, 64);
    }
    if (lane == 0) {
      float m = fmaxf(sqrtf(nrm) * (1.f / 77.f), 1e-8f);
      outScore[(size_t)b * 64 + j] = dot * (1.f / 77.f) * rnA / m;
    }
  }
}

// ---------- launcher ----------
extern "C" void kernel_launch(void* const* d_in, const int* in_sizes, int n_in,
                              void* d_out, int out_size, void* d_ws, size_t ws_size,
                              hipStream_t stream) {
  (void)in_sizes; (void)n_in; (void)out_size; (void)ws_size;
  const float* img = (const float*)d_in[0];
  const float* txt = (const float*)d_in[1];
  const float* Wi  = (const float*)d_in[2];
  const float* bi  = (const float*)d_in[3];
  const float* Wt  = (const float*)d_in[4];
  const float* bt  = (const float*)d_in[5];
  const float* Wq  = (const float*)d_in[6];
  const float* bq  = (const float*)d_in[7];
  const float* Wk  = (const float*)d_in[8];
  const float* bk  = (const float*)d_in[9];
  const float* Wv  = (const float*)d_in[10];
  const float* bv  = (const float*)d_in[11];
  const float* Wo  = (const float*)d_in[12];
  const float* bo  = (const float*)d_in[13];
  float* out = (float*)d_out;

  constexpr size_t MI = (size_t)BATCH * NP;   // 12544
  constexpr size_t MT = (size_t)BATCH * TL;   // 4928

  // region map — no aliasing (ws is 256 MB, we use ~98 MB)
  constexpr size_t O_AIMG  = 0;
  constexpr size_t O_QBUF  = O_AIMG + MI * 1024 * 2;
  constexpr size_t O_ATTNB = O_QBUF + MI * 512 * 2;
  constexpr size_t O_TEXTB = O_ATTNB + MI * 512 * 2;
  constexpr size_t O_PTXTB = O_TEXTB + MT * 1024 * 2;
  constexpr size_t O_KV    = O_PTXTB + MT * 512 * 2;
  constexpr size_t O_WTT   = O_KV + MT * 1024 * 2;
  constexpr size_t O_WQT   = O_WTT + 1024 * 512 * 2;
  constexpr size_t O_WKT   = O_WQT + 512 * 512 * 2;
  constexpr size_t O_WVT   = O_WKT + 512 * 512 * 2;            // contiguous after WKT
  constexpr size_t O_WOT   = O_WVT + 512 * 512 * 2;
  constexpr size_t O_WIB   = O_WOT + 512 * 512 * 2;            // Wi bf16 [1024][512]
  constexpr size_t O_WIWQT = O_WIB + 1024 * 512 * 2;           // (Wi@Wq)^T [512][1024]
  constexpr size_t O_WALL  = O_WIWQT + 512 * 1024 * 2;
  constexpr size_t SZ_WALL = (size_t)BATCH * 8 * 196 * 80 * 2;
  constexpr size_t O_PART  = O_WALL + SZ_WALL;                 // partA||partC
  constexpr size_t O_BIASQ = O_PART + 262144;
  constexpr size_t O_BQP   = O_BIASQ + 4096;                   // 16x512 partials

  char* ws = (char*)d_ws;
  short* aimg   = (short*)(ws + O_AIMG);
  short* qBuf   = (short*)(ws + O_QBUF);
  short* attnB  = (short*)(ws + O_ATTNB);
  short* textB  = (short*)(ws + O_TEXTB);
  short* ptxtB  = (short*)(ws + O_PTXTB);
  short* kvBuf  = (short*)(ws + O_KV);
  short* wtt    = (short*)(ws + O_WTT);
  short* wqt    = (short*)(ws + O_WQT);
  short* wkt    = (short*)(ws + O_WKT);
  short* wvt    = (short*)(ws + O_WVT);
  short* wot    = (short*)(ws + O_WOT);
  short* wiB    = (short*)(ws + O_WIB);
  short* wiwqT  = (short*)(ws + O_WIWQT);
  short* wAll   = (short*)(ws + O_WALL);
  float* partA  = (float*)(ws + O_PART);
  float* partC  = (float*)(ws + O_PART + 131072);
  float* biasQ  = (float*)(ws + O_BIASQ);
  float* bqPart = (float*)(ws + O_BQP);

  // output layout (floats)
  float* oScore = out;                                    // 64*64
  float* oAttn  = out + 4096;                             // 64*196*512
  float* oW     = oAttn + MI * 512;                       // 64*196*77
  float* oAvg   = oW + (size_t)BATCH * NP * TL;           // 64*512
  float* oCls   = oAvg + (size_t)BATCH * DM;              // 64*512
  float* oPtxt  = oCls + (size_t)BATCH * DM;              // 64*77*512

  // prep: img transpose FIRST (6 blk/CU, 25.9KB LDS) + weight/txt/zero/bias work
  prep_kernel<<<dim3(4176), 256, 0, stream>>>(
      Wi, Wt, Wq, Wk, Wv, Wo, wiB, wtt, wqt, wkt, wvt, wot,
      txt, textB, partA, bi, bqPart, img, aimg);

  // gt1: fold (64, finalizes biasQ) + proj_txt (308, fused cls sum)
  gemm_two<<<dim3(372), 256, 0, stream>>>(
      64,
      wqt, wiB, partA, partA, nullptr, wiwqT, nullptr, 1 << 30, 512, 512, 1024, 3,
      bqPart, bq, biasQ,
      textB, wtt, bt, bt, oPtxt, ptxtB, partC, 77, (int)MT, 1024, 512, 2);

  // gt2: q direct (784, aimg @ WiWq + biasQ) + kv (616, ptxt @ [Wk|Wv])
  gemm_two<<<dim3(1400), 256, 0, stream>>>(
      784,
      aimg, wiwqT, biasQ, biasQ, nullptr, qBuf, nullptr, 1 << 30, (int)MI, 1024, 512, 2,
      nullptr, nullptr, nullptr,
      ptxtB, wkt, bk, bv, nullptr, kvBuf, nullptr, 1 << 30, (int)MT, 512, 1024, 3);

  attn_kernel<<<dim3(512), 256, 0, stream>>>(qBuf, kvBuf, attnB, wAll);

  // merged: attn output projection (784, fused avg column-sum) + meanw (6272)
  gemm_meanw<<<dim3(7056), 256, 0, stream>>>(
      784, attnB, wot, bo, bo, oAttn, nullptr, partA, 196, (int)MI, 512, 512, 2,
      wAll, oW);

  final_kernel<<<dim3(64), 256, 0, stream>>>(partA, partC, oAvg, oCls, oScore);
}

// Round 18
// 127.458 us; speedup vs baseline: 1.0092x; 1.0092x over previous
//
#include <hip/hip_runtime.h>
#include <hip/hip_bf16.h>

// ---------- types ----------
typedef __attribute__((ext_vector_type(8))) short s16x8;
typedef __attribute__((ext_vector_type(4))) short s16x4;
typedef __attribute__((ext_vector_type(4))) float f32x4;

__device__ __forceinline__ float b2f(short s) {
  return __uint_as_float(((unsigned)(unsigned short)s) << 16);
}
__device__ __forceinline__ short f2b(float f) {
  unsigned u = __float_as_uint(f);
  unsigned r = u + 0x7fffu + ((u >> 16) & 1u);   // round-to-nearest-even
  return (short)(r >> 16);
}

// async global->LDS, 16B per lane; LDS dest = wave-uniform base + lane*16
__device__ __forceinline__ void gload16(const short* g, short* l) {
  __builtin_amdgcn_global_load_lds((const __attribute__((address_space(1))) void*)g,
                                   (__attribute__((address_space(3))) void*)l, 16, 0, 0);
}

// ---------- problem constants ----------
#define BATCH 64
#define NP    196
#define TL    77
#define DM    512
#define CIMG  1024

// unified GEMM LDS carve (50176 B total -> 3 blocks/CU)
#define SM_AS   0          // short As[2][64*64]   = 16384 B
#define SM_BS   16384      // short Bs[2][128*64]  = 32768 B
#define SM_PC   49152      // float pc[2][128]     = 1024 B
#define SM_SIZE 50176

// stream-transpose of one (b, c-stripe-of-64): the source region
// img[b][c0..c0+64)[*] is ONE CONTIGUOUS 50KB block -> flat float4 streaming
// load (fully coalesced, sequential), f2b into a 64x202 bf16 LDS tile
// (stride 202 -> ~4-way max bank aliasing on the transposed read), then
// s16x8 stores. Needs 25856 B of LDS.
__device__ __forceinline__ void img_transpose_stripe(
    short* lds, const float* __restrict__ img, short* __restrict__ aimg, int bb) {
  int tid = threadIdx.x;
  int b = bb >> 4, c0 = (bb & 15) * 64;
  const float4* src = (const float4*)(img + (size_t)b * CIMG * NP + (size_t)c0 * NP);
  // load: 3136 float4s flat; f = cl*49 + c4  (row cl = c-local, 49 f4/row)
  #pragma unroll
  for (int it = 0; it < 13; it++) {
    int f = it * 256 + tid;
    if (f < 3136) {
      float4 v = src[f];
      int cl = f / 49, c4 = f - cl * 49;
      s16x4 o;
      o[0] = f2b(v.x); o[1] = f2b(v.y); o[2] = f2b(v.z); o[3] = f2b(v.w);
      *(s16x4*)&lds[cl * 202 + c4 * 4] = o;
    }
  }
  __syncthreads();
  // store: 196 n-rows x 8 c-chunks of 8 shorts
  short* ob = aimg + (size_t)b * NP * CIMG;
  #pragma unroll
  for (int it = 0; it < 7; it++) {
    int task = it * 256 + tid;
    if (task < 1568) {
      int n = task >> 3, cc = task & 7;
      s16x8 o;
      #pragma unroll
      for (int q = 0; q < 8; q++) o[q] = lds[(cc * 8 + q) * 202 + n];
      *(s16x8*)&ob[(size_t)n * CIMG + c0 + cc * 8] = o;
    }
  }
}

// ---------- prep (1-D grid, 3664 blocks; transpose half FIRST) ----------
// [0,512):      img stream-transpose stripes 0..511 (6 blk/CU, 25.9KB LDS)
// [512,1024):   Wi f32 -> wiB bf16 straight cast
// [1024,1536):  Wt transpose
// [1536,2560):  Wq,Wk,Wv,Wo transposes
// [2560,3584):  txt cast
// [3584,3648):  zero partA||partC
// [3648,3664):  biasQ e-slice partials
__global__ __launch_bounds__(256)
void prep_kernel(const float* __restrict__ Wi, const float* __restrict__ Wt,
                 const float* __restrict__ Wq, const float* __restrict__ Wk,
                 const float* __restrict__ Wv, const float* __restrict__ Wo,
                 short* __restrict__ wiB, short* __restrict__ WtT,
                 short* __restrict__ WqT, short* __restrict__ WkT,
                 short* __restrict__ WvT, short* __restrict__ WoT,
                 const float* __restrict__ txt, short* __restrict__ textB,
                 float* __restrict__ partZero,
                 const float* __restrict__ bi, float* __restrict__ bqPart,
                 const float* __restrict__ img, short* __restrict__ aimg) {
  int blk = blockIdx.x;
  __shared__ __align__(16) short sprep[64 * 202];   // 25856 B; overlaid below
  int tid = threadIdx.x;
  if (blk < 512) {
    img_transpose_stripe(sprep, img, aimg, blk);    // stripes 0..511
    return;
  }
  if (blk < 1024) {
    int gid = (blk - 512) * 256 + tid;
    float4 v = ((const float4*)Wi)[gid];
    s16x4 o;
    o[0] = f2b(v.x); o[1] = f2b(v.y); o[2] = f2b(v.z); o[3] = f2b(v.w);
    ((s16x4*)wiB)[gid] = o;
    return;
  }
  if (blk < 2560) {
    float* raw = (float*)sprep;          // 32x33 f32 = 4224 B < 25856 B
    const float* W; short* WT; int K, k0, n0;
    if (blk < 1536) {
      int bb = blk - 1024;
      W = Wt; WT = WtT; K = 1024;
      k0 = (bb & 31) * 32; n0 = (bb >> 5) * 32;
    } else {
      int bb = blk - 1536;
      int w = bb >> 8;
      switch (w) {
        case 0: W = Wq; WT = WqT; break;
        case 1: W = Wk; WT = WkT; break;
        case 2: W = Wv; WT = WvT; break;
        default: W = Wo; WT = WoT; break;
      }
      K = 512;
      k0 = (bb & 15) * 32; n0 = ((bb >> 4) & 15) * 32;
    }
    int tx = tid & 31, ty = tid >> 5;   // ty 0..7
    #pragma unroll
    for (int i = 0; i < 4; i++)
      raw[(ty + i * 8) * 33 + tx] = W[(size_t)(k0 + ty + i * 8) * 512 + n0 + tx];
    __syncthreads();
    #pragma unroll
    for (int i = 0; i < 4; i++)
      WT[(size_t)(n0 + ty + i * 8) * K + k0 + tx] = f2b(raw[tx * 33 + ty + i * 8]);
    return;
  }
  if (blk < 3584) {
    int fb = blk - 2560;
    int n4 = (int)((size_t)BATCH * TL * 1024 / 4);
    for (int i = fb * 256 + tid; i < n4; i += 1024 * 256) {
      float4 v = ((const float4*)txt)[i];
      s16x4 o;
      o[0] = f2b(v.x); o[1] = f2b(v.y); o[2] = f2b(v.z); o[3] = f2b(v.w);
      ((s16x4*)textB)[i] = o;
    }
    return;
  }
  if (blk < 3648) {
    int id = (blk - 3584) * 256 + tid;   // exactly [0,16384)
    ((float4*)partZero)[id] = make_float4(0.f, 0.f, 0.f, 0.f);
    return;
  }
  // biasQ partial: slice s covers e in [s*32, s*32+32)
  int s = blk - 3648, d0 = tid * 2;
  float a0 = 0.f, a1 = 0.f;
  #pragma unroll
  for (int i = 0; i < 32; i++) {
    int e = s * 32 + i;
    float bie = bi[e];
    a0 += bie * Wq[(size_t)e * 512 + d0];
    a1 += bie * Wq[(size_t)e * 512 + d0 + 1];
  }
  bqPart[s * 512 + d0] = a0;
  bqPart[s * 512 + d0 + 1] = a1;
}

// ---------- MFMA GEMM core (round-11 proven): BM=64, BN=128, BK=64 ----------
// Depth-2 counted-vmcnt pipeline (vmcnt never 0 mid-loop) + issue-early
// staging: vmcnt(6) -> barrier -> ds_read frags -> lgkmcnt(0) -> barrier ->
// stage(t+2) -> MFMAx16. XOR-swizzled LDS. 50KB LDS -> 3 blocks/CU.
__device__ __forceinline__ void gemm_core(
    short (*As)[64 * 64], short (*Bs)[128 * 64], float (*pc)[128],
    const short* __restrict__ A, const short* __restrict__ BT,
    const float* __restrict__ bias, const float* __restrict__ bias2,
    float* __restrict__ outF, short* __restrict__ outB,
    float* __restrict__ part, int rowsPerB,
    int bm, int bn, int M, int K, int N) {
  int tid = threadIdx.x, wave = tid >> 6, lane = tid & 63;
  int r = lane & 15, kg = lane >> 4, rr7 = r & 7;
  int wr = (wave >> 1) * 32, wc = (wave & 1) * 64;
  int l8 = lane >> 3, g8 = lane & 7;
  int scol = ((g8 ^ l8) << 3);          // swizzled source k-offset (elems)
  const short* gA = A + (size_t)(bm + wave * 16 + l8) * K + scol;
  const short* gB = BT + (size_t)(bn + wave * 32 + l8) * K + scol;

  f32x4 acc[2][4];
  #pragma unroll
  for (int i = 0; i < 2; i++)
    #pragma unroll
    for (int j = 0; j < 4; j++) acc[i][j] = (f32x4){0.f, 0.f, 0.f, 0.f};

  auto stage = [&](int buf, int k0) {   // 6 global_load_lds per wave
    #pragma unroll
    for (int j = 0; j < 2; j++)
      gload16(gA + (size_t)(j * 8) * K + k0, &As[buf][(wave * 16 + j * 8) * 64]);
    #pragma unroll
    for (int j = 0; j < 4; j++)
      gload16(gB + (size_t)(j * 8) * K + k0, &Bs[buf][(wave * 32 + j * 8) * 64]);
  };

  if (part) pc[tid >> 7][tid & 127] = 0.f;
  stage(0, 0);
  stage(1, 64);
  int nt = K >> 6;
  for (int t = 0; t < nt; t++) {
    if (t + 1 < nt) asm volatile("s_waitcnt vmcnt(6)" ::: "memory");
    else            asm volatile("s_waitcnt vmcnt(0)" ::: "memory");
    __builtin_amdgcn_s_barrier();
    asm volatile("" ::: "memory");
    int buf = t & 1;
    s16x8 af[2][2], bf[4][2];
    #pragma unroll
    for (int ks = 0; ks < 2; ks++) {
      int gsw = (((ks << 2) + kg) ^ rr7) << 3;   // swizzled granule (elems)
      #pragma unroll
      for (int i = 0; i < 2; i++)
        af[i][ks] = *(const s16x8*)&As[buf][(wr + i * 16 + r) * 64 + gsw];
      #pragma unroll
      for (int j = 0; j < 4; j++)
        bf[j][ks] = *(const s16x8*)&Bs[buf][(wc + j * 16 + r) * 64 + gsw];
    }
    asm volatile("s_waitcnt lgkmcnt(0)" ::: "memory");   // reads COMPLETE
    __builtin_amdgcn_sched_barrier(0);
    if (t + 2 < nt) {
      __builtin_amdgcn_s_barrier();      // all waves done sampling buf
      asm volatile("" ::: "memory");
      stage(buf, (t + 2) << 6);          // prefetch flies under the MFMAs
      __builtin_amdgcn_sched_barrier(0);
    }
    #pragma unroll
    for (int ks = 0; ks < 2; ks++)
      #pragma unroll
      for (int i = 0; i < 2; i++)
        #pragma unroll
        for (int j = 0; j < 4; j++)
          acc[i][j] = __builtin_amdgcn_mfma_f32_16x16x32_bf16(af[i][ks], bf[j][ks], acc[i][j], 0, 0, 0);
  }

  // epilogue: C/D layout col=lane&15, row=(lane>>4)*4+reg
  int bnd = part ? (bm / rowsPerB + 1) * rowsPerB : 0x7fffffff;
  #pragma unroll
  for (int i = 0; i < 2; i++) {
    float ps[4][2] = {{0.f, 0.f}, {0.f, 0.f}, {0.f, 0.f}, {0.f, 0.f}};
    #pragma unroll
    for (int rr = 0; rr < 4; rr++) {
      int row = bm + wr + i * 16 + kg * 4 + rr;
      int slot = (row >= bnd) ? 1 : 0;
      #pragma unroll
      for (int j = 0; j < 4; j++) {
        int col = bn + wc + j * 16 + r;
        float bval = (col < 512) ? bias[col] : bias2[col - 512];
        float v = acc[i][j][rr] + bval;
        if (outF) outF[(size_t)row * N + col] = v;
        if (outB) outB[(size_t)row * N + col] = f2b(v);
        ps[j][slot] += v;
      }
    }
    if (part) {
      #pragma unroll
      for (int j = 0; j < 4; j++) {
        atomicAdd(&pc[0][wc + j * 16 + r], ps[j][0]);
        if (ps[j][1] != 0.f) atomicAdd(&pc[1][wc + j * 16 + r], ps[j][1]);
      }
    }
  }
  if (part) {
    __syncthreads();
    int slot = tid >> 7, c = tid & 127;
    int b = bm / rowsPerB + slot;
    bool valid = (slot == 0) || (bnd <= bm + 63);
    if (valid && b < M / rowsPerB)
      atomicAdd(&part[(size_t)b * 512 + bn + c], pc[slot][c]);
  }
}

// two independent GEMMs + img-transpose range in one launch.
// GEMM set 0: [0,g0); GEMM set 1: [g0,gT0); transpose: [gT0,gridDim)
// handling stripes (bid-gT0)+512. g0 multiple of 8.
// Set 0 optionally finalizes biasQ = bqVec + sum_s bqPart[s][:].
__global__ __launch_bounds__(256)
void gemm_two(int g0, int gT0,
    const float* timg, short* taimg,
    const short* A0, const short* BT0, const float* b0a, const float* b0b,
    float* oF0, short* oB0, float* p0, int rpb0, int M0, int K0, int N0, int lny0,
    const float* bqPart, const float* bqVec, float* bqOut,
    const short* A1, const short* BT1, const float* b1a, const float* b1b,
    float* oF1, short* oB1, float* p1, int rpb1, int M1, int K1, int N1, int lny1) {
  __shared__ __align__(16) char smem[SM_SIZE];
  short (*As)[64 * 64] = (short (*)[64 * 64])(smem + SM_AS);
  short (*Bs)[128 * 64] = (short (*)[128 * 64])(smem + SM_BS);
  float (*pc)[128] = (float (*)[128])(smem + SM_PC);
  int bid = blockIdx.x;
  if (bid >= gT0) {
    img_transpose_stripe((short*)smem, timg, taimg, bid - gT0 + 512);
    return;
  }
  if (bid < g0) {
    int nwg = g0, orig = bid;
    int q8 = nwg >> 3, rm = nwg & 7;
    int xcd = orig & 7, idx = orig >> 3;
    int lin = (xcd < rm ? xcd * (q8 + 1) : rm * (q8 + 1) + (xcd - rm) * q8) + idx;
    if (bqOut && threadIdx.x < 16 && lin * 16 + 15 < 512) {
      int d = lin * 16 + threadIdx.x;
      float a = bqVec[d];
      #pragma unroll
      for (int s = 0; s < 16; s++) a += bqPart[s * 512 + d];
      bqOut[d] = a;
    }
    int bx = lin >> lny0, by = lin & ((1 << lny0) - 1);
    gemm_core(As, Bs, pc, A0, BT0, b0a, b0b, oF0, oB0, p0, rpb0,
              bx * 64, by * 128, M0, K0, N0);
  } else {
    int nwg = gT0 - g0, orig = bid - g0;
    int q8 = nwg >> 3, rm = nwg & 7;
    int xcd = orig & 7, idx = orig >> 3;
    int lin = (xcd < rm ? xcd * (q8 + 1) : rm * (q8 + 1) + (xcd - rm) * q8) + idx;
    int bx = lin >> lny1, by = lin & ((1 << lny1) - 1);
    gemm_core(As, Bs, pc, A1, BT1, b1a, b1b, oF1, oB1, p1, rpb1,
              bx * 64, by * 128, M1, K1, N1);
  }
}

// attn-out GEMM [0,g1) + meanw range [g1,..): 2 (b,n) rows per 256-thr block.
__global__ __launch_bounds__(256)
void gemm_meanw(int g1,
    const short* __restrict__ A, const short* __restrict__ BT,
    const float* __restrict__ bias, const float* __restrict__ bias2,
    float* __restrict__ outF, short* __restrict__ outB,
    float* __restrict__ part, int rowsPerB, int M, int K, int N, int lny,
    const short* __restrict__ wAll, float* __restrict__ outW) {
  __shared__ __align__(16) char smem[SM_SIZE];
  short (*As)[64 * 64] = (short (*)[64 * 64])(smem + SM_AS);
  short (*Bs)[128 * 64] = (short (*)[128 * 64])(smem + SM_BS);
  float (*pc)[128] = (float (*)[128])(smem + SM_PC);
  int bid = blockIdx.x, tid = threadIdx.x;
  if (bid >= g1) {
    float* ws = (float*)smem;             // [2][8][80] overlay, 5.1KB
    int half = tid >> 7, t = tid & 127;
    int bn = (bid - g1) * 2 + half;       // < 12544
    int b = bn / 196, n = bn - b * 196;
    if (t < 80) {
      int h = t / 10, cc = t - h * 10;
      s16x8 v = *(const s16x8*)&wAll[(((size_t)(b * 8 + h)) * 196 + n) * 80 + cc * 8];
      #pragma unroll
      for (int j = 0; j < 8; j++) ws[half * 640 + h * 80 + cc * 8 + j] = b2f(v[j]);
    }
    __syncthreads();
    if (t < 77) {
      float s = 0.f;
      #pragma unroll
      for (int h = 0; h < 8; h++) s += ws[half * 640 + h * 80 + t];
      outW[(size_t)bn * 77 + t] = s * 0.125f;
    }
    return;
  }
  int nwg = g1, orig = bid;
  int q8 = nwg >> 3, rm = nwg & 7;
  int xcd = orig & 7, idx = orig >> 3;
  int lin = (xcd < rm ? xcd * (q8 + 1) : rm * (q8 + 1) + (xcd - rm) * q8) + idx;
  int bx = lin >> lny, by = lin & ((1 << lny) - 1);
  gemm_core(As, Bs, pc, A, BT, bias, bias2, outF, outB, part, rowsPerB,
            bx * 64, by * 128, M, K, N);
}

// ---------- MFMA attention: one block per (b,h), 4 waves ----------
// kvB layout: [B*TL][1024] bf16, cols 0..511 = k, 512..1023 = v
// wAll layout: [bh][196][80] bf16 (cols 77..79 junk-zero)
__global__ __launch_bounds__(256)
void attn_kernel(const short* __restrict__ qB, const short* __restrict__ kvB,
                 short* __restrict__ attnB, short* __restrict__ wAll) {
  __shared__ short kls[80 * 72];
  __shared__ short vtls[64 * 104];
  __shared__ short pls[4][16 * 104];
  int bh = blockIdx.x, b = bh >> 3, h = bh & 7;
  int tid = threadIdx.x, wave = tid >> 6, lane = tid & 63;
  int r = lane & 15, kg = lane >> 4;

  for (int i = lane; i < 208; i += 64)
    *(s16x8*)&pls[wave][i * 8] = (s16x8){0, 0, 0, 0, 0, 0, 0, 0};

  for (int idx = tid; idx < 80 * 8; idx += 256) {
    int t = idx >> 3, c8 = (idx & 7) << 3;
    s16x8 v = (s16x8){0, 0, 0, 0, 0, 0, 0, 0};
    if (t < 77) v = *(const s16x8*)&kvB[((size_t)(b * TL + t)) * 1024 + h * 64 + c8];
    *(s16x8*)&kls[t * 72 + c8] = v;
  }
  for (int idx = tid; idx < 64 * 12; idx += 256) {
    int d = idx & 63, t8 = idx >> 6;
    s16x8 v;
    #pragma unroll
    for (int j = 0; j < 8; j++) {
      int t = t8 * 8 + j;
      v[j] = (t < 77) ? kvB[((size_t)(b * TL + t)) * 1024 + 512 + h * 64 + d] : (short)0;
    }
    *(s16x8*)&vtls[d * 104 + t8 * 8] = v;
  }
  __syncthreads();

  s16x8 vf[4][3];
  #pragma unroll
  for (int jd = 0; jd < 4; jd++)
    #pragma unroll
    for (int kk = 0; kk < 3; kk++)
      vf[jd][kk] = *(const s16x8*)&vtls[(jd * 16 + r) * 104 + kg * 8 + kk * 32];

  for (int mf = wave; mf < 13; mf += 4) {
    int m0 = mf * 16;
    int qrow = m0 + r; if (qrow > 195) qrow = 195;
    const short* qp = qB + ((size_t)(b * NP + qrow)) * 512 + h * 64 + kg * 8;
    s16x8 qf0 = *(const s16x8*)qp;
    s16x8 qf1 = *(const s16x8*)(qp + 32);

    f32x4 s[5];
    #pragma unroll
    for (int j = 0; j < 5; j++) s[j] = (f32x4){0.f, 0.f, 0.f, 0.f};
    __builtin_amdgcn_s_setprio(1);
    #pragma unroll
    for (int j = 0; j < 5; j++) {
      s16x8 kf0 = *(const s16x8*)&kls[(j * 16 + r) * 72 + kg * 8];
      s16x8 kf1 = *(const s16x8*)&kls[(j * 16 + r) * 72 + kg * 8 + 32];
      s[j] = __builtin_amdgcn_mfma_f32_16x16x32_bf16(qf0, kf0, s[j], 0, 0, 0);
      s[j] = __builtin_amdgcn_mfma_f32_16x16x32_bf16(qf1, kf1, s[j], 0, 0, 0);
    }
    __builtin_amdgcn_s_setprio(0);
    float st[5][4];
    float mx[4] = {-3e38f, -3e38f, -3e38f, -3e38f};
    #pragma unroll
    for (int j = 0; j < 5; j++) {
      bool valid = (j * 16 + r) < 77;
      #pragma unroll
      for (int rr = 0; rr < 4; rr++) {
        float v = valid ? s[j][rr] * 0.125f : -3e38f;
        st[j][rr] = v;
        mx[rr] = fmaxf(mx[rr], v);
      }
    }
    #pragma unroll
    for (int m = 1; m < 16; m <<= 1)
      #pragma unroll
      for (int rr = 0; rr < 4; rr++)
        mx[rr] = fmaxf(mx[rr], __shfl_xor(mx[rr], m, 64));
    float sm[4] = {0.f, 0.f, 0.f, 0.f};
    #pragma unroll
    for (int j = 0; j < 5; j++)
      #pragma unroll
      for (int rr = 0; rr < 4; rr++) {
        float e = __expf(st[j][rr] - mx[rr]);
        st[j][rr] = e;
        sm[rr] += e;
      }
    #pragma unroll
    for (int m = 1; m < 16; m <<= 1)
      #pragma unroll
      for (int rr = 0; rr < 4; rr++)
        sm[rr] += __shfl_xor(sm[rr], m, 64);
    float rinv[4];
    #pragma unroll
    for (int rr = 0; rr < 4; rr++) rinv[rr] = 1.f / sm[rr];

    #pragma unroll
    for (int j = 0; j < 5; j++) {
      int t = j * 16 + r;
      #pragma unroll
      for (int rr = 0; rr < 4; rr++)
        pls[wave][(kg * 4 + rr) * 104 + t] = f2b(st[j][rr] * rinv[rr]);
    }
    asm volatile("s_waitcnt lgkmcnt(0)" ::: "memory");
    __builtin_amdgcn_sched_barrier(0);

    // vectorized wAll store: 16 rows x 10 chunks of 8 shorts (stride 80)
    #pragma unroll
    for (int i2 = 0; i2 < 3; i2++) {
      int cid = lane + i2 * 64;
      if (cid < 160) {
        int row = cid / 10, cc = cid - row * 10;
        int grow = m0 + row;
        if (grow < 196)
          *(s16x8*)&wAll[((size_t)bh * 196 + grow) * 80 + cc * 8] =
              *(const s16x8*)&pls[wave][row * 104 + cc * 8];
      }
    }

    s16x8 pf[3];
    #pragma unroll
    for (int kk = 0; kk < 3; kk++)
      pf[kk] = *(const s16x8*)&pls[wave][r * 104 + kg * 8 + kk * 32];
    f32x4 o[4];
    #pragma unroll
    for (int jd = 0; jd < 4; jd++) o[jd] = (f32x4){0.f, 0.f, 0.f, 0.f};
    __builtin_amdgcn_s_setprio(1);
    #pragma unroll
    for (int kk = 0; kk < 3; kk++)
      #pragma unroll
      for (int jd = 0; jd < 4; jd++)
        o[jd] = __builtin_amdgcn_mfma_f32_16x16x32_bf16(pf[kk], vf[jd][kk], o[jd], 0, 0, 0);
    __builtin_amdgcn_s_setprio(0);
    #pragma unroll
    for (int jd = 0; jd < 4; jd++)
      #pragma unroll
      for (int rr = 0; rr < 4; rr++) {
        int row = m0 + kg * 4 + rr;
        if (row < 196)
          attnB[((size_t)(b * NP + row)) * 512 + h * 64 + jd * 16 + r] = f2b(o[jd][rr]);
      }
  }
}

// ---------- fused finalize: means + l2-normalize + 64x64 cosine scores ----------
__global__ __launch_bounds__(256)
void final_kernel(const float* __restrict__ partA, const float* __restrict__ partC,
                  float* __restrict__ oAvg, float* __restrict__ oCls,
                  float* __restrict__ outScore) {
  __shared__ float alsA[512];
  __shared__ float red[4];
  __shared__ float rnAs;
  int b = blockIdx.x, tid = threadIdx.x;
  int wave = tid >> 6, lane = tid & 63;
  int c0 = tid * 2;
  float a0 = partA[(size_t)b * 512 + c0] * (1.f / 196.f);
  float a1 = partA[(size_t)b * 512 + c0 + 1] * (1.f / 196.f);
  float t0 = partC[(size_t)b * 512 + c0] * (1.f / 77.f);
  float t1 = partC[(size_t)b * 512 + c0 + 1] * (1.f / 77.f);
  oAvg[(size_t)b * 512 + c0] = a0; oAvg[(size_t)b * 512 + c0 + 1] = a1;
  oCls[(size_t)b * 512 + c0] = t0; oCls[(size_t)b * 512 + c0 + 1] = t1;
  alsA[c0] = a0; alsA[c0 + 1] = a1;
  float sq = a0 * a0 + a1 * a1;
  #pragma unroll
  for (int off = 32; off > 0; off >>= 1) sq += __shfl_down(sq, off, 64);
  if (lane == 0) red[wave] = sq;
  __syncthreads();
  if (tid == 0) rnAs = 1.f / fmaxf(sqrtf(red[0] + red[1] + red[2] + red[3]), 1e-8f);
  __syncthreads();
  float rnA = rnAs;
  float aReg[8];
  #pragma unroll
  for (int k = 0; k < 8; k++) aReg[k] = alsA[lane + k * 64];
  for (int j = wave * 16; j < wave * 16 + 16; j++) {
    float dot = 0.f, nrm = 0.f;
    #pragma unroll
    for (int k = 0; k < 8; k++) {
      float cv = partC[(size_t)j * 512 + lane + k * 64];
      dot += aReg[k] * cv;
      nrm += cv * cv;
    }
    #pragma unroll
    for (int off = 32; off > 0; off >>= 1) {
      dot += __shfl_down(dot, off, 64);
      nrm += __shfl_down(nrm, off, 64);
    }
    if (lane == 0) {
      float m = fmaxf(sqrtf(nrm) * (1.f / 77.f), 1e-8f);
      outScore[(size_t)b * 64 + j] = dot * (1.f / 77.f) * rnA / m;
    }
  }
}

// ---------- launcher ----------
extern "C" void kernel_launch(void* const* d_in, const int* in_sizes, int n_in,
                              void* d_out, int out_size, void* d_ws, size_t ws_size,
                              hipStream_t stream) {
  (void)in_sizes; (void)n_in; (void)out_size; (void)ws_size;
  const float* img = (const float*)d_in[0];
  const float* txt = (const float*)d_in[1];
  const float* Wi  = (const float*)d_in[2];
  const float* bi  = (const float*)d_in[3];
  const float* Wt  = (const float*)d_in[4];
  const float* bt  = (const float*)d_in[5];
  const float* Wq  = (const float*)d_in[6];
  const float* bq  = (const float*)d_in[7];
  const float* Wk  = (const float*)d_in[8];
  const float* bk  = (const float*)d_in[9];
  const float* Wv  = (const float*)d_in[10];
  const float* bv  = (const float*)d_in[11];
  const float* Wo  = (const float*)d_in[12];
  const float* bo  = (const float*)d_in[13];
  float* out = (float*)d_out;

  constexpr size_t MI = (size_t)BATCH * NP;   // 12544
  constexpr size_t MT = (size_t)BATCH * TL;   // 4928

  // region map — no aliasing (ws is 256 MB, we use ~98 MB)
  constexpr size_t O_AIMG  = 0;
  constexpr size_t O_QBUF  = O_AIMG + MI * 1024 * 2;
  constexpr size_t O_ATTNB = O_QBUF + MI * 512 * 2;
  constexpr size_t O_TEXTB = O_ATTNB + MI * 512 * 2;
  constexpr size_t O_PTXTB = O_TEXTB + MT * 1024 * 2;
  constexpr size_t O_KV    = O_PTXTB + MT * 512 * 2;
  constexpr size_t O_WTT   = O_KV + MT * 1024 * 2;
  constexpr size_t O_WQT   = O_WTT + 1024 * 512 * 2;
  constexpr size_t O_WKT   = O_WQT + 512 * 512 * 2;
  constexpr size_t O_WVT   = O_WKT + 512 * 512 * 2;            // contiguous after WKT
  constexpr size_t O_WOT   = O_WVT + 512 * 512 * 2;
  constexpr size_t O_WIB   = O_WOT + 512 * 512 * 2;            // Wi bf16 [1024][512]
  constexpr size_t O_WIWQT = O_WIB + 1024 * 512 * 2;           // (Wi@Wq)^T [512][1024]
  constexpr size_t O_WALL  = O_WIWQT + 512 * 1024 * 2;
  constexpr size_t SZ_WALL = (size_t)BATCH * 8 * 196 * 80 * 2;
  constexpr size_t O_PART  = O_WALL + SZ_WALL;                 // partA||partC
  constexpr size_t O_BIASQ = O_PART + 262144;
  constexpr size_t O_BQP   = O_BIASQ + 4096;                   // 16x512 partials

  char* ws = (char*)d_ws;
  short* aimg   = (short*)(ws + O_AIMG);
  short* qBuf   = (short*)(ws + O_QBUF);
  short* attnB  = (short*)(ws + O_ATTNB);
  short* textB  = (short*)(ws + O_TEXTB);
  short* ptxtB  = (short*)(ws + O_PTXTB);
  short* kvBuf  = (short*)(ws + O_KV);
  short* wtt    = (short*)(ws + O_WTT);
  short* wqt    = (short*)(ws + O_WQT);
  short* wkt    = (short*)(ws + O_WKT);
  short* wvt    = (short*)(ws + O_WVT);
  short* wot    = (short*)(ws + O_WOT);
  short* wiB    = (short*)(ws + O_WIB);
  short* wiwqT  = (short*)(ws + O_WIWQT);
  short* wAll   = (short*)(ws + O_WALL);
  float* partA  = (float*)(ws + O_PART);
  float* partC  = (float*)(ws + O_PART + 131072);
  float* biasQ  = (float*)(ws + O_BIASQ);
  float* bqPart = (float*)(ws + O_BQP);

  // output layout (floats)
  float* oScore = out;                                    // 64*64
  float* oAttn  = out + 4096;                             // 64*196*512
  float* oW     = oAttn + MI * 512;                       // 64*196*77
  float* oAvg   = oW + (size_t)BATCH * NP * TL;           // 64*512
  float* oCls   = oAvg + (size_t)BATCH * DM;              // 64*512
  float* oPtxt  = oCls + (size_t)BATCH * DM;              // 64*77*512

  // prep: transpose stripes 0..511 first (6 blk/CU) + weight/txt/zero/bias work
  prep_kernel<<<dim3(3664), 256, 0, stream>>>(
      Wi, Wt, Wq, Wk, Wv, Wo, wiB, wtt, wqt, wkt, wvt, wot,
      txt, textB, partA, bi, bqPart, img, aimg);

  // gt1: fold (64, finalizes biasQ) + proj_txt (308, fused cls sum)
  //      + transpose stripes 512..1023 (overlapped with GEMM compute)
  gemm_two<<<dim3(884), 256, 0, stream>>>(
      64, 372, img, aimg,
      wqt, wiB, partA, partA, nullptr, wiwqT, nullptr, 1 << 30, 512, 512, 1024, 3,
      bqPart, bq, biasQ,
      textB, wtt, bt, bt, oPtxt, ptxtB, partC, 77, (int)MT, 1024, 512, 2);

  // gt2: q direct (784, aimg @ WiWq + biasQ) + kv (616, ptxt @ [Wk|Wv])
  gemm_two<<<dim3(1400), 256, 0, stream>>>(
      784, 1400, nullptr, nullptr,
      aimg, wiwqT, biasQ, biasQ, nullptr, qBuf, nullptr, 1 << 30, (int)MI, 1024, 512, 2,
      nullptr, nullptr, nullptr,
      ptxtB, wkt, bk, bv, nullptr, kvBuf, nullptr, 1 << 30, (int)MT, 512, 1024, 3);

  attn_kernel<<<dim3(512), 256, 0, stream>>>(qBuf, kvBuf, attnB, wAll);

  // merged: attn output projection (784, fused avg column-sum) + meanw (6272)
  gemm_meanw<<<dim3(7056), 256, 0, stream>>>(
      784, attnB, wot, bo, bo, oAttn, nullptr, partA, 196, (int)MI, 512, 512, 2,
      wAll, oW);

  final_kernel<<<dim3(64), 256, 0, stream>>>(partA, partC, oAvg, oCls, oScore);
}

// Round 19
// 124.440 us; speedup vs baseline: 1.0337x; 1.0243x over previous
//
#include <hip/hip_runtime.h>
#include <hip/hip_bf16.h>

// ---------- types ----------
typedef __attribute__((ext_vector_type(8))) short s16x8;
typedef __attribute__((ext_vector_type(4))) short s16x4;
typedef __attribute__((ext_vector_type(4))) float f32x4;

__device__ __forceinline__ float b2f(short s) {
  return __uint_as_float(((unsigned)(unsigned short)s) << 16);
}
__device__ __forceinline__ short f2b(float f) {
  unsigned u = __float_as_uint(f);
  unsigned r = u + 0x7fffu + ((u >> 16) & 1u);   // round-to-nearest-even
  return (short)(r >> 16);
}

// async global->LDS, 16B per lane; LDS dest = wave-uniform base + lane*16
__device__ __forceinline__ void gload16(const short* g, short* l) {
  __builtin_amdgcn_global_load_lds((const __attribute__((address_space(1))) void*)g,
                                   (__attribute__((address_space(3))) void*)l, 16, 0, 0);
}

// ---------- problem constants ----------
#define BATCH 64
#define NP    196
#define TL    77
#define DM    512
#define CIMG  1024

// unified GEMM LDS carve (50176 B total -> 3 blocks/CU)
#define SM_AS   0          // short As[2][64*64]   = 16384 B
#define SM_BS   16384      // short Bs[2][128*64]  = 32768 B
#define SM_PC   49152      // float pc[2][128]     = 1024 B
#define SM_SIZE 50176

// ---------- prep (1-D grid, 3152 blocks) ----------
// [0,512):      Wi f32 -> wiB bf16 straight cast
// [512,1024):   Wt transpose
// [1024,2048):  Wq,Wk,Wv,Wo transposes
// [2048,3072):  txt cast
// [3072,3136):  zero partA||partC
// [3136,3152):  biasQ e-slice partials
__global__ __launch_bounds__(256)
void prep_kernel(const float* __restrict__ Wi, const float* __restrict__ Wt,
                 const float* __restrict__ Wq, const float* __restrict__ Wk,
                 const float* __restrict__ Wv, const float* __restrict__ Wo,
                 short* __restrict__ wiB, short* __restrict__ WtT,
                 short* __restrict__ WqT, short* __restrict__ WkT,
                 short* __restrict__ WvT, short* __restrict__ WoT,
                 const float* __restrict__ txt, short* __restrict__ textB,
                 float* __restrict__ partZero,
                 const float* __restrict__ bi, float* __restrict__ bqPart) {
  int blk = blockIdx.x;
  __shared__ float raw[32 * 33];
  int tid = threadIdx.x;
  if (blk < 512) {
    int gid = blk * 256 + tid;
    float4 v = ((const float4*)Wi)[gid];
    s16x4 o;
    o[0] = f2b(v.x); o[1] = f2b(v.y); o[2] = f2b(v.z); o[3] = f2b(v.w);
    ((s16x4*)wiB)[gid] = o;
    return;
  }
  if (blk < 2048) {
    const float* W; short* WT; int K, k0, n0;
    if (blk < 1024) {
      int bb = blk - 512;
      W = Wt; WT = WtT; K = 1024;
      k0 = (bb & 31) * 32; n0 = (bb >> 5) * 32;
    } else {
      int bb = blk - 1024;
      int w = bb >> 8;
      switch (w) {
        case 0: W = Wq; WT = WqT; break;
        case 1: W = Wk; WT = WkT; break;
        case 2: W = Wv; WT = WvT; break;
        default: W = Wo; WT = WoT; break;
      }
      K = 512;
      k0 = (bb & 15) * 32; n0 = ((bb >> 4) & 15) * 32;
    }
    int tx = tid & 31, ty = tid >> 5;   // ty 0..7
    #pragma unroll
    for (int i = 0; i < 4; i++)
      raw[(ty + i * 8) * 33 + tx] = W[(size_t)(k0 + ty + i * 8) * 512 + n0 + tx];
    __syncthreads();
    #pragma unroll
    for (int i = 0; i < 4; i++)
      WT[(size_t)(n0 + ty + i * 8) * K + k0 + tx] = f2b(raw[tx * 33 + ty + i * 8]);
    return;
  }
  if (blk < 3072) {
    int fb = blk - 2048;
    int n4 = (int)((size_t)BATCH * TL * 1024 / 4);
    for (int i = fb * 256 + tid; i < n4; i += 1024 * 256) {
      float4 v = ((const float4*)txt)[i];
      s16x4 o;
      o[0] = f2b(v.x); o[1] = f2b(v.y); o[2] = f2b(v.z); o[3] = f2b(v.w);
      ((s16x4*)textB)[i] = o;
    }
    return;
  }
  if (blk < 3136) {
    int id = (blk - 3072) * 256 + tid;   // exactly [0,16384)
    ((float4*)partZero)[id] = make_float4(0.f, 0.f, 0.f, 0.f);
    return;
  }
  // biasQ partial: slice s covers e in [s*32, s*32+32)
  int s = blk - 3136, d0 = tid * 2;
  float a0 = 0.f, a1 = 0.f;
  #pragma unroll
  for (int i = 0; i < 32; i++) {
    int e = s * 32 + i;
    float bie = bi[e];
    a0 += bie * Wq[(size_t)e * 512 + d0];
    a1 += bie * Wq[(size_t)e * 512 + d0 + 1];
  }
  bqPart[s * 512 + d0] = a0;
  bqPart[s * 512 + d0 + 1] = a1;
}

// ---------- MFMA GEMM core (round-11 proven): BM=64, BN=128, BK=64 ----------
// Depth-2 counted-vmcnt pipeline (vmcnt never 0 mid-loop) + issue-early
// staging: vmcnt(6) -> barrier -> ds_read frags -> lgkmcnt(0) -> barrier ->
// stage(t+2) -> MFMAx16. XOR-swizzled LDS. 50KB LDS -> 3 blocks/CU.
__device__ __forceinline__ void gemm_core(
    short (*As)[64 * 64], short (*Bs)[128 * 64], float (*pc)[128],
    const short* __restrict__ A, const short* __restrict__ BT,
    const float* __restrict__ bias, const float* __restrict__ bias2,
    float* __restrict__ outF, short* __restrict__ outB,
    float* __restrict__ part, int rowsPerB,
    int bm, int bn, int M, int K, int N) {
  int tid = threadIdx.x, wave = tid >> 6, lane = tid & 63;
  int r = lane & 15, kg = lane >> 4, rr7 = r & 7;
  int wr = (wave >> 1) * 32, wc = (wave & 1) * 64;
  int l8 = lane >> 3, g8 = lane & 7;
  int scol = ((g8 ^ l8) << 3);          // swizzled source k-offset (elems)
  const short* gA = A + (size_t)(bm + wave * 16 + l8) * K + scol;
  const short* gB = BT + (size_t)(bn + wave * 32 + l8) * K + scol;

  f32x4 acc[2][4];
  #pragma unroll
  for (int i = 0; i < 2; i++)
    #pragma unroll
    for (int j = 0; j < 4; j++) acc[i][j] = (f32x4){0.f, 0.f, 0.f, 0.f};

  auto stage = [&](int buf, int k0) {   // 6 global_load_lds per wave
    #pragma unroll
    for (int j = 0; j < 2; j++)
      gload16(gA + (size_t)(j * 8) * K + k0, &As[buf][(wave * 16 + j * 8) * 64]);
    #pragma unroll
    for (int j = 0; j < 4; j++)
      gload16(gB + (size_t)(j * 8) * K + k0, &Bs[buf][(wave * 32 + j * 8) * 64]);
  };

  if (part) pc[tid >> 7][tid & 127] = 0.f;
  stage(0, 0);
  stage(1, 64);
  int nt = K >> 6;
  for (int t = 0; t < nt; t++) {
    if (t + 1 < nt) asm volatile("s_waitcnt vmcnt(6)" ::: "memory");
    else            asm volatile("s_waitcnt vmcnt(0)" ::: "memory");
    __builtin_amdgcn_s_barrier();
    asm volatile("" ::: "memory");
    int buf = t & 1;
    s16x8 af[2][2], bf[4][2];
    #pragma unroll
    for (int ks = 0; ks < 2; ks++) {
      int gsw = (((ks << 2) + kg) ^ rr7) << 3;   // swizzled granule (elems)
      #pragma unroll
      for (int i = 0; i < 2; i++)
        af[i][ks] = *(const s16x8*)&As[buf][(wr + i * 16 + r) * 64 + gsw];
      #pragma unroll
      for (int j = 0; j < 4; j++)
        bf[j][ks] = *(const s16x8*)&Bs[buf][(wc + j * 16 + r) * 64 + gsw];
    }
    asm volatile("s_waitcnt lgkmcnt(0)" ::: "memory");   // reads COMPLETE
    __builtin_amdgcn_sched_barrier(0);
    if (t + 2 < nt) {
      __builtin_amdgcn_s_barrier();      // all waves done sampling buf
      asm volatile("" ::: "memory");
      stage(buf, (t + 2) << 6);          // prefetch flies under the MFMAs
      __builtin_amdgcn_sched_barrier(0);
    }
    #pragma unroll
    for (int ks = 0; ks < 2; ks++)
      #pragma unroll
      for (int i = 0; i < 2; i++)
        #pragma unroll
        for (int j = 0; j < 4; j++)
          acc[i][j] = __builtin_amdgcn_mfma_f32_16x16x32_bf16(af[i][ks], bf[j][ks], acc[i][j], 0, 0, 0);
  }

  // epilogue: C/D layout col=lane&15, row=(lane>>4)*4+reg
  int bnd = part ? (bm / rowsPerB + 1) * rowsPerB : 0x7fffffff;
  #pragma unroll
  for (int i = 0; i < 2; i++) {
    float ps[4][2] = {{0.f, 0.f}, {0.f, 0.f}, {0.f, 0.f}, {0.f, 0.f}};
    #pragma unroll
    for (int rr = 0; rr < 4; rr++) {
      int row = bm + wr + i * 16 + kg * 4 + rr;
      int slot = (row >= bnd) ? 1 : 0;
      #pragma unroll
      for (int j = 0; j < 4; j++) {
        int col = bn + wc + j * 16 + r;
        float bval = (col < 512) ? bias[col] : bias2[col - 512];
        float v = acc[i][j][rr] + bval;
        if (outF) outF[(size_t)row * N + col] = v;
        if (outB) outB[(size_t)row * N + col] = f2b(v);
        ps[j][slot] += v;
      }
    }
    if (part) {
      #pragma unroll
      for (int j = 0; j < 4; j++) {
        atomicAdd(&pc[0][wc + j * 16 + r], ps[j][0]);
        if (ps[j][1] != 0.f) atomicAdd(&pc[1][wc + j * 16 + r], ps[j][1]);
      }
    }
  }
  if (part) {
    __syncthreads();
    int slot = tid >> 7, c = tid & 127;
    int b = bm / rowsPerB + slot;
    bool valid = (slot == 0) || (bnd <= bm + 63);
    if (valid && b < M / rowsPerB)
      atomicAdd(&part[(size_t)b * 512 + bn + c], pc[slot][c]);
  }
}

// stream-transpose of one (b, c-stripe-of-64): the source region
// img[b][c0..c0+64)[*] is ONE CONTIGUOUS 50KB block -> flat float4 streaming
// load (fully coalesced, sequential), f2b into a 64x202 bf16 LDS tile
// (stride 202 -> ~4-way max bank aliasing on the transposed read), then
// s16x8 stores. Uses 25.9KB of the unified 50KB smem.
__device__ __forceinline__ void img_transpose_stripe(
    short* lds, const float* __restrict__ img, short* __restrict__ aimg, int bb) {
  int tid = threadIdx.x;
  int b = bb >> 4, c0 = (bb & 15) * 64;
  const float4* src = (const float4*)(img + (size_t)b * CIMG * NP + (size_t)c0 * NP);
  // load: 3136 float4s flat; f = cl*49 + c4  (row cl = c-local, 49 f4/row)
  #pragma unroll
  for (int it = 0; it < 13; it++) {
    int f = it * 256 + tid;
    if (f < 3136) {
      float4 v = src[f];
      int cl = f / 49, c4 = f - cl * 49;
      s16x4 o;
      o[0] = f2b(v.x); o[1] = f2b(v.y); o[2] = f2b(v.z); o[3] = f2b(v.w);
      *(s16x4*)&lds[cl * 202 + c4 * 4] = o;
    }
  }
  __syncthreads();
  // store: 196 n-rows x 8 c-chunks of 8 shorts
  short* ob = aimg + (size_t)b * NP * CIMG;
  #pragma unroll
  for (int it = 0; it < 7; it++) {
    int task = it * 256 + tid;
    if (task < 1568) {
      int n = task >> 3, cc = task & 7;
      s16x8 o;
      #pragma unroll
      for (int q = 0; q < 8; q++) o[q] = lds[(cc * 8 + q) * 202 + n];
      *(s16x8*)&ob[(size_t)n * CIMG + c0 + cc * 8] = o;
    }
  }
}

// two independent GEMMs + optional img-transpose range in one launch.
// GEMM set 0: [0,g0); GEMM set 1: [g0,gT0); transpose: [gT0,gridDim).
// g0 must be a multiple of 8 for set1's XCD swizzle alignment.
// Set 0 optionally finalizes biasQ = bqVec + sum_s bqPart[s][:].
__global__ __launch_bounds__(256)
void gemm_two(int g0, int gT0,
    const float* timg, short* taimg,
    const short* A0, const short* BT0, const float* b0a, const float* b0b,
    float* oF0, short* oB0, float* p0, int rpb0, int M0, int K0, int N0, int lny0,
    const float* bqPart, const float* bqVec, float* bqOut,
    const short* A1, const short* BT1, const float* b1a, const float* b1b,
    float* oF1, short* oB1, float* p1, int rpb1, int M1, int K1, int N1, int lny1) {
  __shared__ __align__(16) char smem[SM_SIZE];
  short (*As)[64 * 64] = (short (*)[64 * 64])(smem + SM_AS);
  short (*Bs)[128 * 64] = (short (*)[128 * 64])(smem + SM_BS);
  float (*pc)[128] = (float (*)[128])(smem + SM_PC);
  int bid = blockIdx.x;
  if (bid >= gT0) {
    img_transpose_stripe((short*)smem, timg, taimg, bid - gT0);
    return;
  }
  if (bid < g0) {
    int nwg = g0, orig = bid;
    int q8 = nwg >> 3, rm = nwg & 7;
    int xcd = orig & 7, idx = orig >> 3;
    int lin = (xcd < rm ? xcd * (q8 + 1) : rm * (q8 + 1) + (xcd - rm) * q8) + idx;
    if (bqOut && threadIdx.x < 16 && lin * 16 + 15 < 512) {
      int d = lin * 16 + threadIdx.x;
      float a = bqVec[d];
      #pragma unroll
      for (int s = 0; s < 16; s++) a += bqPart[s * 512 + d];
      bqOut[d] = a;
    }
    int bx = lin >> lny0, by = lin & ((1 << lny0) - 1);
    gemm_core(As, Bs, pc, A0, BT0, b0a, b0b, oF0, oB0, p0, rpb0,
              bx * 64, by * 128, M0, K0, N0);
  } else {
    int nwg = gT0 - g0, orig = bid - g0;
    int q8 = nwg >> 3, rm = nwg & 7;
    int xcd = orig & 7, idx = orig >> 3;
    int lin = (xcd < rm ? xcd * (q8 + 1) : rm * (q8 + 1) + (xcd - rm) * q8) + idx;
    int bx = lin >> lny1, by = lin & ((1 << lny1) - 1);
    gemm_core(As, Bs, pc, A1, BT1, b1a, b1b, oF1, oB1, p1, rpb1,
              bx * 64, by * 128, M1, K1, N1);
  }
}

// attn-out GEMM [0,g1) + meanw range [g1,..): 2 (b,n) rows per 256-thr block.
__global__ __launch_bounds__(256)
void gemm_meanw(int g1,
    const short* __restrict__ A, const short* __restrict__ BT,
    const float* __restrict__ bias, const float* __restrict__ bias2,
    float* __restrict__ outF, short* __restrict__ outB,
    float* __restrict__ part, int rowsPerB, int M, int K, int N, int lny,
    const short* __restrict__ wAll, float* __restrict__ outW) {
  __shared__ __align__(16) char smem[SM_SIZE];
  short (*As)[64 * 64] = (short (*)[64 * 64])(smem + SM_AS);
  short (*Bs)[128 * 64] = (short (*)[128 * 64])(smem + SM_BS);
  float (*pc)[128] = (float (*)[128])(smem + SM_PC);
  int bid = blockIdx.x, tid = threadIdx.x;
  if (bid >= g1) {
    float* ws = (float*)smem;             // [2][8][80] overlay, 5.1KB
    int half = tid >> 7, t = tid & 127;
    int bn = (bid - g1) * 2 + half;       // < 12544
    int b = bn / 196, n = bn - b * 196;
    if (t < 80) {
      int h = t / 10, cc = t - h * 10;
      s16x8 v = *(const s16x8*)&wAll[(((size_t)(b * 8 + h)) * 196 + n) * 80 + cc * 8];
      #pragma unroll
      for (int j = 0; j < 8; j++) ws[half * 640 + h * 80 + cc * 8 + j] = b2f(v[j]);
    }
    __syncthreads();
    if (t < 77) {
      float s = 0.f;
      #pragma unroll
      for (int h = 0; h < 8; h++) s += ws[half * 640 + h * 80 + t];
      outW[(size_t)bn * 77 + t] = s * 0.125f;
    }
    return;
  }
  int nwg = g1, orig = bid;
  int q8 = nwg >> 3, rm = nwg & 7;
  int xcd = orig & 7, idx = orig >> 3;
  int lin = (xcd < rm ? xcd * (q8 + 1) : rm * (q8 + 1) + (xcd - rm) * q8) + idx;
  int bx = lin >> lny, by = lin & ((1 << lny) - 1);
  gemm_core(As, Bs, pc, A, BT, bias, bias2, outF, outB, part, rowsPerB,
            bx * 64, by * 128, M, K, N);
}

// ---------- MFMA attention: one block per (b,h), 4 waves ----------
// kvB layout: [B*TL][1024] bf16, cols 0..511 = k, 512..1023 = v
// wAll layout: [bh][196][80] bf16 (cols 77..79 junk-zero)
__global__ __launch_bounds__(256)
void attn_kernel(const short* __restrict__ qB, const short* __restrict__ kvB,
                 short* __restrict__ attnB, short* __restrict__ wAll) {
  __shared__ short kls[80 * 72];
  __shared__ short vtls[64 * 104];
  __shared__ short pls[4][16 * 104];
  int bh = blockIdx.x, b = bh >> 3, h = bh & 7;
  int tid = threadIdx.x, wave = tid >> 6, lane = tid & 63;
  int r = lane & 15, kg = lane >> 4;

  for (int i = lane; i < 208; i += 64)
    *(s16x8*)&pls[wave][i * 8] = (s16x8){0, 0, 0, 0, 0, 0, 0, 0};

  for (int idx = tid; idx < 80 * 8; idx += 256) {
    int t = idx >> 3, c8 = (idx & 7) << 3;
    s16x8 v = (s16x8){0, 0, 0, 0, 0, 0, 0, 0};
    if (t < 77) v = *(const s16x8*)&kvB[((size_t)(b * TL + t)) * 1024 + h * 64 + c8];
    *(s16x8*)&kls[t * 72 + c8] = v;
  }
  for (int idx = tid; idx < 64 * 12; idx += 256) {
    int d = idx & 63, t8 = idx >> 6;
    s16x8 v;
    #pragma unroll
    for (int j = 0; j < 8; j++) {
      int t = t8 * 8 + j;
      v[j] = (t < 77) ? kvB[((size_t)(b * TL + t)) * 1024 + 512 + h * 64 + d] : (short)0;
    }
    *(s16x8*)&vtls[d * 104 + t8 * 8] = v;
  }
  __syncthreads();

  s16x8 vf[4][3];
  #pragma unroll
  for (int jd = 0; jd < 4; jd++)
    #pragma unroll
    for (int kk = 0; kk < 3; kk++)
      vf[jd][kk] = *(const s16x8*)&vtls[(jd * 16 + r) * 104 + kg * 8 + kk * 32];

  for (int mf = wave; mf < 13; mf += 4) {
    int m0 = mf * 16;
    int qrow = m0 + r; if (qrow > 195) qrow = 195;
    const short* qp = qB + ((size_t)(b * NP + qrow)) * 512 + h * 64 + kg * 8;
    s16x8 qf0 = *(const s16x8*)qp;
    s16x8 qf1 = *(const s16x8*)(qp + 32);

    f32x4 s[5];
    #pragma unroll
    for (int j = 0; j < 5; j++) s[j] = (f32x4){0.f, 0.f, 0.f, 0.f};
    __builtin_amdgcn_s_setprio(1);
    #pragma unroll
    for (int j = 0; j < 5; j++) {
      s16x8 kf0 = *(const s16x8*)&kls[(j * 16 + r) * 72 + kg * 8];
      s16x8 kf1 = *(const s16x8*)&kls[(j * 16 + r) * 72 + kg * 8 + 32];
      s[j] = __builtin_amdgcn_mfma_f32_16x16x32_bf16(qf0, kf0, s[j], 0, 0, 0);
      s[j] = __builtin_amdgcn_mfma_f32_16x16x32_bf16(qf1, kf1, s[j], 0, 0, 0);
    }
    __builtin_amdgcn_s_setprio(0);
    float st[5][4];
    float mx[4] = {-3e38f, -3e38f, -3e38f, -3e38f};
    #pragma unroll
    for (int j = 0; j < 5; j++) {
      bool valid = (j * 16 + r) < 77;
      #pragma unroll
      for (int rr = 0; rr < 4; rr++) {
        float v = valid ? s[j][rr] * 0.125f : -3e38f;
        st[j][rr] = v;
        mx[rr] = fmaxf(mx[rr], v);
      }
    }
    #pragma unroll
    for (int m = 1; m < 16; m <<= 1)
      #pragma unroll
      for (int rr = 0; rr < 4; rr++)
        mx[rr] = fmaxf(mx[rr], __shfl_xor(mx[rr], m, 64));
    float sm[4] = {0.f, 0.f, 0.f, 0.f};
    #pragma unroll
    for (int j = 0; j < 5; j++)
      #pragma unroll
      for (int rr = 0; rr < 4; rr++) {
        float e = __expf(st[j][rr] - mx[rr]);
        st[j][rr] = e;
        sm[rr] += e;
      }
    #pragma unroll
    for (int m = 1; m < 16; m <<= 1)
      #pragma unroll
      for (int rr = 0; rr < 4; rr++)
        sm[rr] += __shfl_xor(sm[rr], m, 64);
    float rinv[4];
    #pragma unroll
    for (int rr = 0; rr < 4; rr++) rinv[rr] = 1.f / sm[rr];

    #pragma unroll
    for (int j = 0; j < 5; j++) {
      int t = j * 16 + r;
      #pragma unroll
      for (int rr = 0; rr < 4; rr++)
        pls[wave][(kg * 4 + rr) * 104 + t] = f2b(st[j][rr] * rinv[rr]);
    }
    asm volatile("s_waitcnt lgkmcnt(0)" ::: "memory");
    __builtin_amdgcn_sched_barrier(0);

    // vectorized wAll store: 16 rows x 10 chunks of 8 shorts (stride 80)
    #pragma unroll
    for (int i2 = 0; i2 < 3; i2++) {
      int cid = lane + i2 * 64;
      if (cid < 160) {
        int row = cid / 10, cc = cid - row * 10;
        int grow = m0 + row;
        if (grow < 196)
          *(s16x8*)&wAll[((size_t)bh * 196 + grow) * 80 + cc * 8] =
              *(const s16x8*)&pls[wave][row * 104 + cc * 8];
      }
    }

    s16x8 pf[3];
    #pragma unroll
    for (int kk = 0; kk < 3; kk++)
      pf[kk] = *(const s16x8*)&pls[wave][r * 104 + kg * 8 + kk * 32];
    f32x4 o[4];
    #pragma unroll
    for (int jd = 0; jd < 4; jd++) o[jd] = (f32x4){0.f, 0.f, 0.f, 0.f};
    __builtin_amdgcn_s_setprio(1);
    #pragma unroll
    for (int kk = 0; kk < 3; kk++)
      #pragma unroll
      for (int jd = 0; jd < 4; jd++)
        o[jd] = __builtin_amdgcn_mfma_f32_16x16x32_bf16(pf[kk], vf[jd][kk], o[jd], 0, 0, 0);
    __builtin_amdgcn_s_setprio(0);
    #pragma unroll
    for (int jd = 0; jd < 4; jd++)
      #pragma unroll
      for (int rr = 0; rr < 4; rr++) {
        int row = m0 + kg * 4 + rr;
        if (row < 196)
          attnB[((size_t)(b * NP + row)) * 512 + h * 64 + jd * 16 + r] = f2b(o[jd][rr]);
      }
  }
}

// ---------- fused finalize: means + l2-normalize + 64x64 cosine scores ----------
__global__ __launch_bounds__(256)
void final_kernel(const float* __restrict__ partA, const float* __restrict__ partC,
                  float* __restrict__ oAvg, float* __restrict__ oCls,
                  float* __restrict__ outScore) {
  __shared__ float alsA[512];
  __shared__ float red[4];
  __shared__ float rnAs;
  int b = blockIdx.x, tid = threadIdx.x;
  int wave = tid >> 6, lane = tid & 63;
  int c0 = tid * 2;
  float a0 = partA[(size_t)b * 512 + c0] * (1.f / 196.f);
  float a1 = partA[(size_t)b * 512 + c0 + 1] * (1.f / 196.f);
  float t0 = partC[(size_t)b * 512 + c0] * (1.f / 77.f);
  float t1 = partC[(size_t)b * 512 + c0 + 1] * (1.f / 77.f);
  oAvg[(size_t)b * 512 + c0] = a0; oAvg[(size_t)b * 512 + c0 + 1] = a1;
  oCls[(size_t)b * 512 + c0] = t0; oCls[(size_t)b * 512 + c0 + 1] = t1;
  alsA[c0] = a0; alsA[c0 + 1] = a1;
  float sq = a0 * a0 + a1 * a1;
  #pragma unroll
  for (int off = 32; off > 0; off >>= 1) sq += __shfl_down(sq, off, 64);
  if (lane == 0) red[wave] = sq;
  __syncthreads();
  if (tid == 0) rnAs = 1.f / fmaxf(sqrtf(red[0] + red[1] + red[2] + red[3]), 1e-8f);
  __syncthreads();
  float rnA = rnAs;
  float aReg[8];
  #pragma unroll
  for (int k = 0; k < 8; k++) aReg[k] = alsA[lane + k * 64];
  for (int j = wave * 16; j < wave * 16 + 16; j++) {
    float dot = 0.f, nrm = 0.f;
    #pragma unroll
    for (int k = 0; k < 8; k++) {
      float cv = partC[(size_t)j * 512 + lane + k * 64];
      dot += aReg[k] * cv;
      nrm += cv * cv;
    }
    #pragma unroll
    for (int off = 32; off > 0; off >>= 1) {
      dot += __shfl_down(dot, off, 64);
      nrm += __shfl_down(nrm, off, 64);
    }
    if (lane == 0) {
      float m = fmaxf(sqrtf(nrm) * (1.f / 77.f), 1e-8f);
      outScore[(size_t)b * 64 + j] = dot * (1.f / 77.f) * rnA / m;
    }
  }
}

// ---------- launcher ----------
extern "C" void kernel_launch(void* const* d_in, const int* in_sizes, int n_in,
                              void* d_out, int out_size, void* d_ws, size_t ws_size,
                              hipStream_t stream) {
  (void)in_sizes; (void)n_in; (void)out_size; (void)ws_size;
  const float* img = (const float*)d_in[0];
  const float* txt = (const float*)d_in[1];
  const float* Wi  = (const float*)d_in[2];
  const float* bi  = (const float*)d_in[3];
  const float* Wt  = (const float*)d_in[4];
  const float* bt  = (const float*)d_in[5];
  const float* Wq  = (const float*)d_in[6];
  const float* bq  = (const float*)d_in[7];
  const float* Wk  = (const float*)d_in[8];
  const float* bk  = (const float*)d_in[9];
  const float* Wv  = (const float*)d_in[10];
  const float* bv  = (const float*)d_in[11];
  const float* Wo  = (const float*)d_in[12];
  const float* bo  = (const float*)d_in[13];
  float* out = (float*)d_out;

  constexpr size_t MI = (size_t)BATCH * NP;   // 12544
  constexpr size_t MT = (size_t)BATCH * TL;   // 4928

  // region map — no aliasing (ws is 256 MB, we use ~98 MB)
  constexpr size_t O_AIMG  = 0;
  constexpr size_t O_QBUF  = O_AIMG + MI * 1024 * 2;
  constexpr size_t O_ATTNB = O_QBUF + MI * 512 * 2;
  constexpr size_t O_TEXTB = O_ATTNB + MI * 512 * 2;
  constexpr size_t O_PTXTB = O_TEXTB + MT * 1024 * 2;
  constexpr size_t O_KV    = O_PTXTB + MT * 512 * 2;
  constexpr size_t O_WTT   = O_KV + MT * 1024 * 2;
  constexpr size_t O_WQT   = O_WTT + 1024 * 512 * 2;
  constexpr size_t O_WKT   = O_WQT + 512 * 512 * 2;
  constexpr size_t O_WVT   = O_WKT + 512 * 512 * 2;            // contiguous after WKT
  constexpr size_t O_WOT   = O_WVT + 512 * 512 * 2;
  constexpr size_t O_WIB   = O_WOT + 512 * 512 * 2;            // Wi bf16 [1024][512]
  constexpr size_t O_WIWQT = O_WIB + 1024 * 512 * 2;           // (Wi@Wq)^T [512][1024]
  constexpr size_t O_WALL  = O_WIWQT + 512 * 1024 * 2;
  constexpr size_t SZ_WALL = (size_t)BATCH * 8 * 196 * 80 * 2;
  constexpr size_t O_PART  = O_WALL + SZ_WALL;                 // partA||partC
  constexpr size_t O_BIASQ = O_PART + 262144;
  constexpr size_t O_BQP   = O_BIASQ + 4096;                   // 16x512 partials

  char* ws = (char*)d_ws;
  short* aimg   = (short*)(ws + O_AIMG);
  short* qBuf   = (short*)(ws + O_QBUF);
  short* attnB  = (short*)(ws + O_ATTNB);
  short* textB  = (short*)(ws + O_TEXTB);
  short* ptxtB  = (short*)(ws + O_PTXTB);
  short* kvBuf  = (short*)(ws + O_KV);
  short* wtt    = (short*)(ws + O_WTT);
  short* wqt    = (short*)(ws + O_WQT);
  short* wkt    = (short*)(ws + O_WKT);
  short* wvt    = (short*)(ws + O_WVT);
  short* wot    = (short*)(ws + O_WOT);
  short* wiB    = (short*)(ws + O_WIB);
  short* wiwqT  = (short*)(ws + O_WIWQT);
  short* wAll   = (short*)(ws + O_WALL);
  float* partA  = (float*)(ws + O_PART);
  float* partC  = (float*)(ws + O_PART + 131072);
  float* biasQ  = (float*)(ws + O_BIASQ);
  float* bqPart = (float*)(ws + O_BQP);

  // output layout (floats)
  float* oScore = out;                                    // 64*64
  float* oAttn  = out + 4096;                             // 64*196*512
  float* oW     = oAttn + MI * 512;                       // 64*196*77
  float* oAvg   = oW + (size_t)BATCH * NP * TL;           // 64*512
  float* oCls   = oAvg + (size_t)BATCH * DM;              // 64*512
  float* oPtxt  = oCls + (size_t)BATCH * DM;              // 64*77*512

  prep_kernel<<<dim3(3152), 256, 0, stream>>>(
      Wi, Wt, Wq, Wk, Wv, Wo, wiB, wtt, wqt, wkt, wvt, wot,
      txt, textB, partA, bi, bqPart);

  // gt1: fold (64, finalizes biasQ) + proj_txt (308, fused cls sum)
  //      + stream img transpose (1024 blocks, contiguous 50KB reads)
  gemm_two<<<dim3(1396), 256, 0, stream>>>(
      64, 372, img, aimg,
      wqt, wiB, partA, partA, nullptr, wiwqT, nullptr, 1 << 30, 512, 512, 1024, 3,
      bqPart, bq, biasQ,
      textB, wtt, bt, bt, oPtxt, ptxtB, partC, 77, (int)MT, 1024, 512, 2);

  // gt2: q direct (784, aimg @ WiWq + biasQ) + kv (616, ptxt @ [Wk|Wv])
  gemm_two<<<dim3(1400), 256, 0, stream>>>(
      784, 1400, nullptr, nullptr,
      aimg, wiwqT, biasQ, biasQ, nullptr, qBuf, nullptr, 1 << 30, (int)MI, 1024, 512, 2,
      nullptr, nullptr, nullptr,
      ptxtB, wkt, bk, bv, nullptr, kvBuf, nullptr, 1 << 30, (int)MT, 512, 1024, 3);

  attn_kernel<<<dim3(512), 256, 0, stream>>>(qBuf, kvBuf, attnB, wAll);

  // merged: attn output projection (784, fused avg column-sum) + meanw (6272)
  gemm_meanw<<<dim3(7056), 256, 0, stream>>>(
      784, attnB, wot, bo, bo, oAttn, nullptr, partA, 196, (int)MI, 512, 512, 2,
      wAll, oW);

  final_kernel<<<dim3(64), 256, 0, stream>>>(partA, partC, oAvg, oCls, oScore);
}